// Round 4
// baseline (252.263 us; speedup 1.0000x reference)
//
#include <hip/hip_runtime.h>
#include <math.h>

// MaxMarginLoss: B=4,S=512,D=512,V=32000, gamma=0.5, eps=1e-12
// score[r,v] = (out_norm[r] - tgt_emb[r]) . voc_norm[v]  -> argmax_v (first-idx ties)
// loss = mean over non-pad rows of max(gamma + cos(out,voc[jmax]) - cos(out,voc[tgt]), 0)
//
// R4: bf16 MFMA gemm_bt + fused argmax epilogue, with
//  - XOR bank-swizzle on LDS K-chunks (kills 8.2e6 conflict cycles)
//  - double-buffered global_load_lds staging, ONE barrier per K-step
//  - 3 launches: prep_all / gemm_argmax / row_final_reduce (ticketed final mean)

#define Bb 4
#define Ss 512
#define Dd 512
#define Vv 32000
#define ROWS (Bb * Ss)          // 2048
#define NTILE_M (ROWS / 128)    // 16
#define NTILE_N (Vv / 128)      // 250
#define VOC_BLOCKS (Vv / 4)     // 8000

typedef __attribute__((ext_vector_type(8))) short bf16x8;
typedef __attribute__((ext_vector_type(4))) float f32x4;

__device__ __forceinline__ float waveReduceSum(float x) {
#pragma unroll
  for (int m = 32; m >= 1; m >>= 1) x += __shfl_xor(x, m, 64);
  return x;
}

__device__ __forceinline__ unsigned short f2bf(float f) {
  unsigned u = __float_as_uint(f);
  unsigned r = (u + 0x7FFFu + ((u >> 16) & 1u)) >> 16;  // RNE; inputs finite
  return (unsigned short)r;
}

// monotonic key: for finite floats, key(a) < key(b) <=> a < b
__device__ __forceinline__ unsigned long long packSC(float s, int c) {
  unsigned b = __float_as_uint(s);
  unsigned key = b ^ ((b & 0x80000000u) ? 0xFFFFFFFFu : 0x80000000u);
  return ((unsigned long long)key << 32) | (unsigned)(~c);  // ~c: ties -> smaller col wins at max
}

__device__ __forceinline__ void async_ld16(const void* g, void* l) {
  __builtin_amdgcn_global_load_lds((const __attribute__((address_space(1))) void*)g,
                                   (__attribute__((address_space(3))) void*)l, 16, 0, 0);
}

// K1: fused prep. blocks [0,8000): vocab rows -> ebf + inv_norm.
//     blocks [8000,10048): preds rows -> o_rows, u_bf, cos_tgt.
//     block 0 additionally zeroes the reduction accumulators.
__global__ __launch_bounds__(256) void prep_all(
    const float* __restrict__ preds, const float* __restrict__ emb,
    const int* __restrict__ target,
    float* __restrict__ o_rows, short* __restrict__ u_bf,
    float* __restrict__ cos_tgt, short* __restrict__ ebf,
    float* __restrict__ inv_norm, float* __restrict__ accum) {
  int tid = threadIdx.x;
  int wave = tid >> 6, lane = tid & 63;
  if (blockIdx.x < VOC_BLOCKS) {
    if (blockIdx.x == 0 && tid < 3) accum[tid] = 0.0f;  // sum, cnt, ticket
    int v = blockIdx.x * 4 + wave;
    const float* e = emb + (size_t)v * Dd;
    float4 x0 = *(const float4*)(e + lane * 8);
    float4 x1 = *(const float4*)(e + lane * 8 + 4);
    float ss = x0.x * x0.x + x0.y * x0.y + x0.z * x0.z + x0.w * x0.w +
               x1.x * x1.x + x1.y * x1.y + x1.z * x1.z + x1.w * x1.w;
    ss = waveReduceSum(ss);
    float inv = 1.0f / fmaxf(sqrtf(ss), 1e-12f);
    bf16x8 o;
    o[0] = (short)f2bf(x0.x * inv); o[1] = (short)f2bf(x0.y * inv);
    o[2] = (short)f2bf(x0.z * inv); o[3] = (short)f2bf(x0.w * inv);
    o[4] = (short)f2bf(x1.x * inv); o[5] = (short)f2bf(x1.y * inv);
    o[6] = (short)f2bf(x1.z * inv); o[7] = (short)f2bf(x1.w * inv);
    *(bf16x8*)(ebf + (size_t)v * Dd + lane * 8) = o;
    if (lane == 0) inv_norm[v] = inv;
  } else {
    int row = blockIdx.x - VOC_BLOCKS;
    int b = row >> 9, s = row & (Ss - 1);
    const float* p = preds + (size_t)b * Dd * Ss + s;
    float x0 = p[(size_t)tid * Ss];
    float x1 = p[(size_t)(tid + 256) * Ss];
    __shared__ float red[12];
    float ss = waveReduceSum(x0 * x0 + x1 * x1);
    if (lane == 0) red[wave] = ss;
    __syncthreads();
    float inv = 1.0f / fmaxf(sqrtf(red[0] + red[1] + red[2] + red[3]), 1e-12f);
    float o0 = x0 * inv, o1 = x1 * inv;
    o_rows[(size_t)row * Dd + tid] = o0;
    o_rows[(size_t)row * Dd + tid + 256] = o1;
    int t = target[row];
    const float* et = emb + (size_t)t * Dd;
    float e0 = et[tid], e1 = et[tid + 256];
    u_bf[(size_t)row * Dd + tid] = (short)f2bf(o0 - e0);
    u_bf[(size_t)row * Dd + tid + 256] = (short)f2bf(o1 - e1);
    float ss2 = waveReduceSum(e0 * e0 + e1 * e1);
    float dt = waveReduceSum(o0 * e0 + o1 * e1);
    if (lane == 0) { red[4 + wave] = ss2; red[8 + wave] = dt; }
    __syncthreads();
    if (tid == 0) {
      float n2 = red[4] + red[5] + red[6] + red[7];
      float dd = red[8] + red[9] + red[10] + red[11];
      cos_tgt[row] = dd * (1.0f / fmaxf(sqrtf(n2), 1e-12f));
    }
  }
}

// K2: 128x128-tile bf16 MFMA GEMM (B^T) + per-row argmax epilogue.
// Double-buffered LDS staging (one barrier per K-step) + XOR bank swizzle.
__global__ __launch_bounds__(256) void gemm_argmax(
    const short* __restrict__ u_bf, const short* __restrict__ ebf,
    unsigned long long* __restrict__ part) {
  __shared__ short sA[2][128 * 32];
  __shared__ short sB[2][128 * 32];
  int tm = blockIdx.x, tn = blockIdx.y;
  int tid = threadIdx.x;
  int w = tid >> 6, lane = tid & 63;
  int wm = w >> 1, wn = w & 1;

  // Staging: wave w stages rows [w*32, w*32+32). LDS dest is forced contiguous
  // (wave-uniform base + lane*16B) = row-major (row=lane>>2, chunk=lane&3).
  // Bank swizzle: physical chunk p holds logical chunk p ^ ((row>>2)&3), so the
  // GLOBAL source chunk for this lane is (lane&3) ^ (((lane>>2)>>2)&3).
  int srow = w * 32 + (lane >> 2);
  int schunk = (lane & 3) ^ ((lane >> 4) & 3);
  const short* gA = u_bf + (size_t)(tm * 128 + srow) * Dd + schunk * 8;
  const short* gB = ebf + (size_t)(tn * 128 + srow) * Dd + schunk * 8;

  // Fragment read: row r=lane&15, logical chunk cc=lane>>4, physical = cc^((r>>2)&3).
  int fr = lane & 15;
  int pchunk = (lane >> 4) ^ ((fr >> 2) & 3);
  int foff = fr * 32 + pchunk * 8;

  f32x4 acc[4][4];
  f32x4 z = {0.f, 0.f, 0.f, 0.f};
#pragma unroll
  for (int mi = 0; mi < 4; ++mi)
#pragma unroll
    for (int ni = 0; ni < 4; ++ni) acc[mi][ni] = z;

  // prologue: stage kk=0 into buf 0
  {
    short* lA = &sA[0][w * 32 * 32];
    short* lB = &sB[0][w * 32 * 32];
    async_ld16(gA, lA);
    async_ld16(gA + 16 * Dd, lA + 16 * 32);
    async_ld16(gB, lB);
    async_ld16(gB + 16 * Dd, lB + 16 * 32);
  }
  for (int kk = 0; kk < Dd / 32; ++kk) {
    __syncthreads();  // buf[kk&1] staged (vmcnt drained); prev compute done
    if (kk < Dd / 32 - 1) {
      int nb = (kk + 1) & 1;
      short* lA = &sA[nb][w * 32 * 32];
      short* lB = &sB[nb][w * 32 * 32];
      const short* ga = gA + (kk + 1) * 32;
      const short* gb = gB + (kk + 1) * 32;
      async_ld16(ga, lA);
      async_ld16(ga + 16 * Dd, lA + 16 * 32);
      async_ld16(gb, lB);
      async_ld16(gb + 16 * Dd, lB + 16 * 32);
    }
    int cb = kk & 1;
    const short* pa = &sA[cb][foff];
    const short* pb = &sB[cb][foff];
    bf16x8 af[4], bg[4];
#pragma unroll
    for (int mi = 0; mi < 4; ++mi)
      af[mi] = *(const bf16x8*)(pa + (wm * 64 + mi * 16) * 32);
#pragma unroll
    for (int ni = 0; ni < 4; ++ni)
      bg[ni] = *(const bf16x8*)(pb + (wn * 64 + ni * 16) * 32);
#pragma unroll
    for (int mi = 0; mi < 4; ++mi)
#pragma unroll
      for (int ni = 0; ni < 4; ++ni)
        acc[mi][ni] = __builtin_amdgcn_mfma_f32_16x16x32_bf16(af[mi], bg[ni], acc[mi][ni], 0, 0, 0);
  }

  // ---- argmax epilogue ----
  // C layout: col = lane&15, row = (lane>>4)*4 + reg
  float bs[4][4];
  int bc[4][4];
  int col0 = tn * 128 + wn * 64 + (lane & 15);
#pragma unroll
  for (int mi = 0; mi < 4; ++mi) {
#pragma unroll
    for (int j = 0; j < 4; ++j) { bs[mi][j] = acc[mi][0][j]; bc[mi][j] = col0; }
#pragma unroll
    for (int ni = 1; ni < 4; ++ni) {
      int c = col0 + ni * 16;
#pragma unroll
      for (int j = 0; j < 4; ++j) {
        float v = acc[mi][ni][j];
        if (v > bs[mi][j]) { bs[mi][j] = v; bc[mi][j] = c; }  // strict >: earliest col kept
      }
    }
  }
#pragma unroll
  for (int m = 1; m < 16; m <<= 1) {
#pragma unroll
    for (int mi = 0; mi < 4; ++mi)
#pragma unroll
      for (int j = 0; j < 4; ++j) {
        float os = __shfl_xor(bs[mi][j], m, 64);
        int oc = __shfl_xor(bc[mi][j], m, 64);
        if (os > bs[mi][j] || (os == bs[mi][j] && oc < bc[mi][j])) {
          bs[mi][j] = os;
          bc[mi][j] = oc;
        }
      }
  }
  __syncthreads();  // done with sA/sB; reuse as merge scratch
  float* sEs = (float*)&sA[0][0];   // [2][128]
  int* sEc = (int*)&sA[0][0] + 256; // [2][128]
  if ((lane & 15) == 0) {
    int q = lane >> 4;
#pragma unroll
    for (int mi = 0; mi < 4; ++mi)
#pragma unroll
      for (int j = 0; j < 4; ++j) {
        int rloc = wm * 64 + mi * 16 + q * 4 + j;
        sEs[wn * 128 + rloc] = bs[mi][j];
        sEc[wn * 128 + rloc] = bc[mi][j];
      }
  }
  __syncthreads();
  if (tid < 128) {
    float s0 = sEs[tid], s1 = sEs[128 + tid];
    int c0 = sEc[tid], c1 = sEc[128 + tid];
    if (s1 > s0 || (s1 == s0 && c1 < c0)) { s0 = s1; c0 = c1; }
    part[(size_t)tn * ROWS + tm * 128 + tid] = packSC(s0, c0);
  }
}

// K3: per row — u64-max merge 250 partials, recompute cos at jmax in fp32,
// hinge, then device-wide masked mean via atomics + last-block ticket.
__global__ __launch_bounds__(256) void row_final_reduce(
    const float* __restrict__ o_rows, const float* __restrict__ emb,
    const float* __restrict__ inv_norm, const float* __restrict__ cos_tgt,
    const int* __restrict__ target, const int* __restrict__ pad_id,
    const unsigned long long* __restrict__ part, float* __restrict__ accum,
    float* __restrict__ out) {
  int wave = threadIdx.x >> 6, lane = threadIdx.x & 63;
  int row = blockIdx.x * 4 + wave;
  unsigned long long best = 0ull;  // any real packed value exceeds 0
  for (int t = lane; t < NTILE_N; t += 64) {
    unsigned long long p = part[(size_t)t * ROWS + row];
    if (p > best) best = p;
  }
#pragma unroll
  for (int m = 1; m < 64; m <<= 1) {
    unsigned long long o = __shfl_xor(best, m, 64);
    if (o > best) best = o;
  }
  int bi = (int)(~(unsigned)(best & 0xFFFFFFFFull));
  const float* o = o_rows + (size_t)row * Dd;
  const float* e = emb + (size_t)bi * Dd;
  float d = 0.f;
#pragma unroll
  for (int i = 0; i < Dd / 64; ++i) d += o[lane + 64 * i] * e[lane + 64 * i];
  d = waveReduceSum(d);
  __shared__ float sdf[4], scn[4];
  if (lane == 0) {
    float cmax = d * inv_norm[bi];
    int t = target[row];
    float df = fmaxf(0.5f + cmax - cos_tgt[row], 0.0f);
    bool ok = (t != pad_id[0]);
    sdf[wave] = ok ? df : 0.0f;
    scn[wave] = ok ? 1.0f : 0.0f;
  }
  __syncthreads();
  if (threadIdx.x == 0) {
    atomicAdd(&accum[0], sdf[0] + sdf[1] + sdf[2] + sdf[3]);
    atomicAdd(&accum[1], scn[0] + scn[1] + scn[2] + scn[3]);
    __threadfence();
    unsigned t = (unsigned)atomicAdd(&accum[2], 1.0f);
    if (t == (unsigned)(ROWS / 4 - 1)) {
      __threadfence();
      volatile float* va = accum;
      out[0] = va[0] / va[1];
    }
  }
}

extern "C" void kernel_launch(void* const* d_in, const int* in_sizes, int n_in,
                              void* d_out, int out_size, void* d_ws, size_t ws_size,
                              hipStream_t stream) {
  const float* preds = (const float*)d_in[0];
  const float* emb = (const float*)d_in[1];
  const int* target = (const int*)d_in[2];
  const int* pad_id = (const int*)d_in[3];
  char* ws = (char*)d_ws;
  // ws layout (bytes), total ~43.3 MB
  float* o_rows = (float*)ws;                               // 2048*512*4 = 4,194,304
  short* u_bf = (short*)(ws + 4194304);                     // 2048*512*2 = 2,097,152
  short* ebf = (short*)(ws + 6291456);                      // 32000*512*2 = 32,768,000
  float* inv_norm = (float*)(ws + 39059456);                // 32000*4 = 128,000
  float* cos_tgt = (float*)(ws + 39187456);                 // 2048*4
  unsigned long long* part = (unsigned long long*)(ws + 39195648);  // 250*2048*8 = 4,096,000
  float* accum = (float*)(ws + 43291648);                   // 3 floats: sum, cnt, ticket

  prep_all<<<VOC_BLOCKS + ROWS, 256, 0, stream>>>(preds, emb, target, o_rows, u_bf,
                                                  cos_tgt, ebf, inv_norm, accum);
  dim3 g(NTILE_M, NTILE_N);
  gemm_argmax<<<g, 256, 0, stream>>>(u_bf, ebf, part);
  row_final_reduce<<<ROWS / 4, 256, 0, stream>>>(o_rows, emb, inv_norm, cos_tgt,
                                                 target, pad_id, part, accum,
                                                 (float*)d_out);
}